// Round 6
// baseline (1666.328 us; speedup 1.0000x reference)
//
#include <hip/hip_runtime.h>
#include <math.h>

constexpr int NB  = 256;
constexpr int NS  = 8;
constexpr int NC  = 8;
constexpr int NH  = 501;
constexpr int NL  = 56;
constexpr int NH2 = 1002;
constexpr int NH3 = 1503;
constexpr int NH4 = 2004;
constexpr int KT  = 1536;   // trio K (3 x 512)
constexpr int KE  = 512;    // edge / fp16 K
constexpr int HV  = 512 * 256;

typedef unsigned short u16;
typedef short bf16x8v __attribute__((ext_vector_type(8)));
typedef _Float16 f16x8v __attribute__((ext_vector_type(8)));
typedef _Float16 f16x4v __attribute__((ext_vector_type(4)));
typedef float f32x4 __attribute__((ext_vector_type(4)));

__device__ __forceinline__ float sigf(float x) { return 1.0f / (1.0f + __expf(-x)); }
__device__ __forceinline__ float tanh2(float x) { return 2.0f * sigf(2.0f * x) - 1.0f; }

__device__ __forceinline__ u16 f2bf(float x) {
  union { float f; unsigned u; } c; c.f = x;
  unsigned r = (c.u + 0x7fffu + ((c.u >> 16) & 1u)) >> 16;
  return (u16)r;
}
__device__ __forceinline__ float bf2f(u16 h) {
  union { float f; unsigned u; } c; c.u = ((unsigned)h) << 16; return c.f;
}

__device__ __forceinline__ void async_copy16(const void* g, void* l) {
  __builtin_amdgcn_global_load_lds(
      (const __attribute__((address_space(1))) unsigned int*)g,
      (__attribute__((address_space(3))) unsigned int*)l, 16, 0, 0);
}

__device__ __forceinline__ f32x4 mfma_bf(bf16x8v a, bf16x8v b, f32x4 c) {
  return __builtin_amdgcn_mfma_f32_16x16x32_bf16(a, b, c, 0, 0, 0);
}
__device__ __forceinline__ f32x4 mfma_h(f16x8v a, f16x8v b, f32x4 c) {
  return __builtin_amdgcn_mfma_f32_16x16x32_f16(a, b, c, 0, 0, 0);
}

__device__ __forceinline__ void storeTrio(u16* __restrict__ T, int b, int h0, const float v[4]) {
  size_t base = (size_t)b * KT;
  if (h0 + 3 < NH) {
    ushort4 hi4, lo4;
    u16 hi, lo;
    hi = f2bf(v[0]); lo = f2bf(v[0] - bf2f(hi)); hi4.x = hi; lo4.x = lo;
    hi = f2bf(v[1]); lo = f2bf(v[1] - bf2f(hi)); hi4.y = hi; lo4.y = lo;
    hi = f2bf(v[2]); lo = f2bf(v[2] - bf2f(hi)); hi4.z = hi; lo4.z = lo;
    hi = f2bf(v[3]); lo = f2bf(v[3] - bf2f(hi)); hi4.w = hi; lo4.w = lo;
    *(ushort4*)&T[base + h0]        = hi4;
    *(ushort4*)&T[base + 512 + h0]  = lo4;
    *(ushort4*)&T[base + 1024 + h0] = hi4;
  } else {
    for (int r = 0; r < 4; ++r) {
      int h = h0 + r;
      if (h < NH) {
        u16 hi = f2bf(v[r]); u16 lo = f2bf(v[r] - bf2f(hi));
        T[base + h] = hi; T[base + 512 + h] = lo; T[base + 1024 + h] = hi;
      }
    }
  }
}

// ---------------- init / pack ----------------

// zero the h=501..511 pad rows of all 58 trio slabs + 28 Xe slots
__global__ __launch_bounds__(256) void kPadZ(u16* __restrict__ trio, _Float16* __restrict__ Xe) {
  int b = blockIdx.x, t = threadIdx.x;
  if (b < 58) {
    u16* T = trio + (size_t)b * ((size_t)NB * KT) + (size_t)t * KT;
#pragma unroll
    for (int seg = 0; seg < 3; ++seg)
      for (int h = 501; h < 512; ++h) T[seg * 512 + h] = 0;
  } else {
    int s = b - 58;
    _Float16* X = Xe + (size_t)s * NB * KE + (size_t)t * KE;
    for (int h = 501; h < 512; ++h) X[h] = (_Float16)0.f;
  }
}

__global__ __launch_bounds__(256) void kInit0(float* __restrict__ out0,
                                              const float* __restrict__ ae_b2,
                                              int* __restrict__ ctr) {
  if (blockIdx.x == 64) {
    if (threadIdx.x < 128) ctr[threadIdx.x] = 0;
    return;
  }
  int e = blockIdx.x * 256 + threadIdx.x;
  int b = e >> 6, r = e & 63;
  int i = r >> 3, jj = r & 7;
  out0[b * 64 + i * 8 + jj] = (jj < i) ? ae_b2[0] : 0.f;
}

__global__ __launch_bounds__(256) void kPack(
    const float* __restrict__ gate_w, const float* __restrict__ map_w,
    const float* __restrict__ w_hh, const float* __restrict__ av_w1,
    const float* __restrict__ ae_w1,
    u16* __restrict__ Wgm, u16* __restrict__ Whh, u16* __restrict__ Wav1,
    u16* __restrict__ Wr3, _Float16* __restrict__ Wl) {
  int r = blockIdx.x;
  for (int k = threadIdx.x; k < 512; k += 256) {
    if (r < 5632) {
      float v = 0.f; u16* dst; int rr;
      if (r < 1024) {
        int h = (r < 512) ? r : r - 512;
        if (h < NH && k < NH) v = (r < 512) ? gate_w[h * NH + k] : map_w[h * NH + k];
        dst = Wgm; rr = r;
      } else if (r < 2560) {
        rr = r - 1024; int g = rr >> 9, h = rr & 511;
        if (h < NH && k < NH) v = w_hh[((size_t)g * NH + h) * NH + k];
        dst = Whh;
      } else if (r < 3584) {
        rr = r - 2560;
        if (rr < NH2 && k < NH) v = av_w1[(size_t)rr * NH + k];
        dst = Wav1;
      } else {
        rr = r - 3584;
        if (rr < NH4 && k < NH) v = ae_w1[(size_t)rr * NH2 + NH + k];
        dst = Wr3;
      }
      u16 hi = f2bf(v); u16 lo = f2bf(v - bf2f(hi));
      dst[(size_t)rr * KT + k] = hi;
      dst[(size_t)rr * KT + 512 + k] = hi;
      dst[(size_t)rr * KT + 1024 + k] = lo;
    } else {
      int m = r - 5632; float v = 0.f;
      if (m < NH4 && k < NH) v = ae_w1[(size_t)m * NH2 + k];
      Wl[(size_t)m * KE + k] = (_Float16)v;
    }
  }
}

__global__ __launch_bounds__(256) void kLin1(const float* __restrict__ z,
                                             const float* __restrict__ w,
                                             const float* __restrict__ bias,
                                             float* __restrict__ g0, u16* __restrict__ GS0) {
  int b = blockIdx.x;
  const float* zr = z + (size_t)b * NL;
  for (int h = threadIdx.x; h < NH; h += 256) {
    const float* wr = w + (size_t)h * NL;
    float acc = bias[h];
#pragma unroll
    for (int l = 0; l < NL; ++l) acc += zr[l] * wr[l];
    g0[h * NB + b] = acc;
    u16 hi = f2bf(acc), lo = f2bf(acc - bf2f(hi));
    GS0[(size_t)b * KT + h] = hi;
    GS0[(size_t)b * KT + 512 + h] = lo;
    GS0[(size_t)b * KT + 1024 + h] = hi;
  }
}

__global__ __launch_bounds__(256) void kGiAll(const float* __restrict__ ne,
                                              const float* __restrict__ w_ih,
                                              const float* __restrict__ b_ih,
                                              float* __restrict__ gi,
                                              float* __restrict__ giT) {
  int r = blockIdx.x, b = threadIdx.x;
  int g = (r >= NH2) ? 2 : ((r >= NH) ? 1 : 0);
  int h = r - g * NH;
  float wv[8];
#pragma unroll
  for (int c = 0; c < 8; ++c) wv[c] = w_ih[r * NC + c];
  float bb = b_ih[r];
  for (int idx = 0; idx < 8; ++idx) {
    float acc = bb;
#pragma unroll
    for (int c = 0; c < 8; ++c) acc += ne[b * 64 + idx * 8 + c] * wv[c];
    gi[((size_t)idx * NH3 + r) * NB + b] = acc;
    giT[((size_t)idx * NB + b) * KT + g * 512 + h] = acc;
  }
}

// ---------------- persistent loop kernel ----------------

// Barrier v2: release-only producer (waitcnt + wbl2, NO invalidate), relaxed poll.
// Correctness without acquire relies on single-assignment cross-phase buffers.
__device__ __forceinline__ void gbar(int* __restrict__ ctr, int p) {
  __syncthreads();
  if (threadIdx.x == 0) {
    __hip_atomic_fetch_add(&ctr[p], 1, __ATOMIC_RELEASE, __HIP_MEMORY_SCOPE_AGENT);
    while (__hip_atomic_load(&ctr[p], __ATOMIC_RELAXED, __HIP_MEMORY_SCOPE_AGENT) < 256) {
      __builtin_amdgcn_s_sleep(1);
    }
  }
  __syncthreads();
}

// GM: gate+map GEMM (M=512+512, N=256, K=1536). 256 blocks = 32 h-tiles x 8 col-tiles.
// mode 0: fused hin assembly (reads RSold, writes RSnew); mode 1: write Pc/Qc.
__device__ void phGM(const u16* __restrict__ Wgm, const u16* __restrict__ Bsrc, int mode,
                     int index, int j, const float* __restrict__ dep,
                     const float* __restrict__ gate_b, const float* __restrict__ map_b,
                     const float* __restrict__ Pcj, const float* __restrict__ Qcj,
                     const float* __restrict__ RSold, float* __restrict__ RSnew,
                     float* __restrict__ hinF, u16* __restrict__ hinT,
                     float* __restrict__ PcO, float* __restrict__ QcO,
                     f32x4* __restrict__ red) {
  const int b = blockIdx.x, t = threadIdx.x, w = t >> 6, l = t & 63;
  const int quad = l >> 4, lan = l & 15;
  const int ht = b & 31, ct = b >> 5;
  const u16* Ag = Wgm + (size_t)(ht * 16 + lan) * KT;
  const u16* Am = Wgm + (size_t)(512 + ht * 16 + lan) * KT;
  const u16* B0 = Bsrc + (size_t)(ct * 32 + lan) * KT;
  const u16* B1 = Bsrc + (size_t)(ct * 32 + 16 + lan) * KT;
  const int kb = w * 384 + quad * 8;
  f32x4 a0 = {0.f,0.f,0.f,0.f}, a1 = a0, a2 = a0, a3 = a0;
#pragma unroll 4
  for (int ks = 0; ks < 12; ++ks) {
    int k = kb + ks * 32;
    bf16x8v bg = *(const bf16x8v*)&B0[k];
    bf16x8v bh = *(const bf16x8v*)&B1[k];
    bf16x8v ag = *(const bf16x8v*)&Ag[k];
    bf16x8v am = *(const bf16x8v*)&Am[k];
    a0 = mfma_bf(ag, bg, a0); a1 = mfma_bf(ag, bh, a1);
    a2 = mfma_bf(am, bg, a2); a3 = mfma_bf(am, bh, a3);
  }
  red[(w * 4 + 0) * 64 + l] = a0;
  red[(w * 4 + 1) * 64 + l] = a1;
  red[(w * 4 + 2) * 64 + l] = a2;
  red[(w * 4 + 3) * 64 + l] = a3;
  __syncthreads();
  if (w < 2) {
    int ns = w;
    f32x4 G = red[(0 * 4 + ns) * 64 + l] + red[(1 * 4 + ns) * 64 + l] +
              red[(2 * 4 + ns) * 64 + l] + red[(3 * 4 + ns) * 64 + l];
    f32x4 M = red[(0 * 4 + 2 + ns) * 64 + l] + red[(1 * 4 + 2 + ns) * 64 + l] +
              red[(2 * 4 + 2 + ns) * 64 + l] + red[(3 * 4 + 2 + ns) * 64 + l];
    int c = ct * 32 + ns * 16 + lan;
    int h0 = ht * 16 + quad * 4;
    if (mode == 1) {
#pragma unroll
      for (int reg = 0; reg < 4; ++reg) {
        int h = h0 + reg;
        if (h < NH) { PcO[h * NB + c] = G[reg]; QcO[h * NB + c] = M[reg]; }
      }
    } else {
      float dj = dep[c * 64 + index * 8 + j];
      float di = dep[c * 64 + index * 8 + index];
      float cnt = (float)(7 - (index - j));
      float vout[4];
#pragma unroll
      for (int reg = 0; reg < 4; ++reg) {
        int h = h0 + reg; float v = 0.f;
        if (h < NH) {
          float gb = gate_b[h], mb = map_b[h];
          float kbv = sigf(gb) * mb;
          float fj = sigf(dj * Pcj[h * NB + c] + gb) * (dj * Qcj[h * NB + c] + mb);
          float rs = RSold[h * NB + c] + fj;
          RSnew[h * NB + c] = rs;
          float fi = sigf(di * G[reg] + gb) * (di * M[reg] + mb);
          v = rs + fi + cnt * kbv;
          hinF[h * NB + c] = v;
        }
        vout[reg] = v;
      }
      storeTrio(hinT, c, h0, vout);
    }
  }
}

// HH: gru_hh GEMM (M=3x512, N=256, K=1536) + GRU combine.
__device__ void phHH(const u16* __restrict__ Whh, const u16* __restrict__ Bsrc,
                     const float* __restrict__ hidF, const float* __restrict__ gi,
                     const float* __restrict__ b_hh,
                     u16* __restrict__ dstT, _Float16* __restrict__ XeSlot,
                     f32x4* __restrict__ red) {
  const int b = blockIdx.x, t = threadIdx.x, w = t >> 6, l = t & 63;
  const int quad = l >> 4, lan = l & 15;
  const int ht = b & 31, ct = b >> 5;
  const u16* Ar = Whh + (size_t)(ht * 16 + lan) * KT;
  const u16* Az = Whh + (size_t)(512 + ht * 16 + lan) * KT;
  const u16* An = Whh + (size_t)(1024 + ht * 16 + lan) * KT;
  const u16* B0 = Bsrc + (size_t)(ct * 32 + lan) * KT;
  const u16* B1 = Bsrc + (size_t)(ct * 32 + 16 + lan) * KT;
  const int kb = w * 384 + quad * 8;
  f32x4 r0 = {0.f,0.f,0.f,0.f}, r1 = r0, z0 = r0, z1 = r0, n0 = r0, n1 = r0;
#pragma unroll 4
  for (int ks = 0; ks < 12; ++ks) {
    int k = kb + ks * 32;
    bf16x8v bg = *(const bf16x8v*)&B0[k];
    bf16x8v bh = *(const bf16x8v*)&B1[k];
    bf16x8v ar = *(const bf16x8v*)&Ar[k];
    bf16x8v az = *(const bf16x8v*)&Az[k];
    bf16x8v an = *(const bf16x8v*)&An[k];
    r0 = mfma_bf(ar, bg, r0); r1 = mfma_bf(ar, bh, r1);
    z0 = mfma_bf(az, bg, z0); z1 = mfma_bf(az, bh, z1);
    n0 = mfma_bf(an, bg, n0); n1 = mfma_bf(an, bh, n1);
  }
  red[(w * 6 + 0) * 64 + l] = r0;
  red[(w * 6 + 1) * 64 + l] = r1;
  red[(w * 6 + 2) * 64 + l] = z0;
  red[(w * 6 + 3) * 64 + l] = z1;
  red[(w * 6 + 4) * 64 + l] = n0;
  red[(w * 6 + 5) * 64 + l] = n1;
  __syncthreads();
  if (w < 2) {
    int ns = w;
    f32x4 Rr = red[(0 * 6 + 0 + ns) * 64 + l] + red[(1 * 6 + 0 + ns) * 64 + l] +
               red[(2 * 6 + 0 + ns) * 64 + l] + red[(3 * 6 + 0 + ns) * 64 + l];
    f32x4 Rz = red[(0 * 6 + 2 + ns) * 64 + l] + red[(1 * 6 + 2 + ns) * 64 + l] +
               red[(2 * 6 + 2 + ns) * 64 + l] + red[(3 * 6 + 2 + ns) * 64 + l];
    f32x4 Rn = red[(0 * 6 + 4 + ns) * 64 + l] + red[(1 * 6 + 4 + ns) * 64 + l] +
               red[(2 * 6 + 4 + ns) * 64 + l] + red[(3 * 6 + 4 + ns) * 64 + l];
    int c = ct * 32 + ns * 16 + lan;
    int h0 = ht * 16 + quad * 4;
    float vout[4];
#pragma unroll
    for (int reg = 0; reg < 4; ++reg) {
      int h = h0 + reg; float v = 0.f;
      if (h < NH) {
        float ir = gi[h * NB + c];
        float iz = gi[(NH + h) * NB + c];
        float inn = gi[(2 * NH + h) * NB + c];
        float rr = sigf(ir + Rr[reg] + b_hh[h]);
        float zz = sigf(iz + Rz[reg] + b_hh[NH + h]);
        float nn = tanh2(inn + rr * (Rn[reg] + b_hh[2 * NH + h]));
        float hd = hidF[h * NB + c];
        v = (1.f - zz) * nn + zz * hd;
      }
      vout[reg] = v;
    }
    storeTrio(dstT, c, h0, vout);
    if (XeSlot) {
      if (h0 + 3 < NH) {
        f16x4v xv; xv[0] = (_Float16)vout[0]; xv[1] = (_Float16)vout[1];
        xv[2] = (_Float16)vout[2]; xv[3] = (_Float16)vout[3];
        *(f16x4v*)&XeSlot[(size_t)c * KE + h0] = xv;
      } else {
        for (int reg = 0; reg < 4; ++reg)
          if (h0 + reg < NH) XeSlot[(size_t)c * KE + h0 + reg] = (_Float16)vout[reg];
      }
    }
  }
}

// PRO: prologue for outer step index>=1. Part1: j=index-1 hin (cached P/Q), fresh RS.
// Part2: hv0 -> Xe slot.
__device__ void phPRO(int index, const float* __restrict__ dep,
                      const float* __restrict__ gate_b, const float* __restrict__ map_b,
                      const float* __restrict__ Pcj, const float* __restrict__ Qcj,
                      float* __restrict__ RSnew, float* __restrict__ hinF, u16* __restrict__ hinT,
                      const float* __restrict__ giT, const float* __restrict__ b_hh,
                      _Float16* __restrict__ Xe0) {
  const int b = blockIdx.x, t = threadIdx.x;
  const int j = index - 1;
  const float cnt = (float)(7 - (index - j));
  if (b < 251) {
#pragma unroll
    for (int hh = 0; hh < 2; ++hh) {
      int h = 2 * b + hh;
      if (h < NH) {
        int c = t;
        float gb = gate_b[h], mb = map_b[h];
        float kbv = sigf(gb) * mb;
        float dj = dep[c * 64 + index * 8 + j];
        float fj = sigf(dj * Pcj[h * NB + c] + gb) * (dj * Qcj[h * NB + c] + mb);
        RSnew[h * NB + c] = fj;
        float v = fj + kbv + cnt * kbv;
        hinF[h * NB + c] = v;
        u16 hi = f2bf(v), lo = f2bf(v - bf2f(hi));
        hinT[(size_t)c * KT + h] = hi;
        hinT[(size_t)c * KT + 512 + h] = lo;
        hinT[(size_t)c * KT + 1024 + h] = hi;
      }
    }
  }
  {
    int c = b;
    const float* g = giT + ((size_t)index * NB + c) * KT;
    for (int h = t; h < NH; h += 256) {
      float rr = sigf(g[h] + b_hh[h]);
      float zz = sigf(g[512 + h] + b_hh[NH + h]);
      float nn = tanh2(g[1024 + h] + rr * b_hh[2 * NH + h]);
      Xe0[(size_t)c * KE + h] = (_Float16)((1.f - zz) * nn);
    }
  }
}

// Buffer versioning: trio slab i -> trio + i*SLOT.
// slabs 0..8: GS (slot0 = graph_state0 trio; slot i+1 = final hv of index i)
// slabs 9..29: 21 intermediate hv steps ; slabs 30..57: 28 hin steps
__global__ __launch_bounds__(256) void kLoop(
    const u16* __restrict__ Wgm, const u16* __restrict__ Whh,
    const float* __restrict__ dep, const float* __restrict__ gate_b,
    const float* __restrict__ map_b, const float* __restrict__ b_hh,
    const float* __restrict__ giN, const float* __restrict__ giT,
    const float* __restrict__ g0,
    u16* __restrict__ trio, float* __restrict__ RSb, float* __restrict__ hinF,
    float* __restrict__ Pc, float* __restrict__ Qc,
    _Float16* __restrict__ Xe, int* __restrict__ ctr) {
  __shared__ f32x4 red[4 * 6 * 64];
  const size_t SLOT = (size_t)NB * KT;
  int p = 0, s = -1, vhv = 0;
  // index 0
  phHH(Whh, trio, g0, giN, b_hh, trio + 1 * SLOT, nullptr, red);
  gbar(ctr, p++);
  phGM(Wgm, trio + 1 * SLOT, 1, 0, 0, dep, gate_b, map_b, nullptr, nullptr,
       nullptr, nullptr, nullptr, nullptr, Pc, Qc, red);
  gbar(ctr, p++);
  for (int index = 1; index < 8; ++index) {
    const float* gi_i = giN + (size_t)index * NH3 * NB;
    int sid0 = index * (index - 1) / 2;
    ++s;
    phPRO(index, dep, gate_b, map_b,
          Pc + (size_t)(index - 1) * HV, Qc + (size_t)(index - 1) * HV,
          RSb + (size_t)s * HV, hinF + (size_t)s * HV, trio + (size_t)(30 + s) * SLOT,
          giT, b_hh, Xe + (size_t)sid0 * NB * KE);
    gbar(ctr, p++);
    int dstSlab = (index == 1) ? 2 : (9 + vhv);
    if (index > 1) vhv++;
    phHH(Whh, trio + (size_t)(30 + s) * SLOT, hinF + (size_t)s * HV, gi_i, b_hh,
         trio + (size_t)dstSlab * SLOT,
         (index - 1 > 0) ? (Xe + (size_t)(sid0 + 1) * NB * KE) : nullptr, red);
    gbar(ctr, p++);
    int prevSlab = dstSlab;
    for (int j = index - 2; j >= 0; --j) {
      int sp = s; ++s;
      phGM(Wgm, trio + (size_t)prevSlab * SLOT, 0, index, j, dep, gate_b, map_b,
           Pc + (size_t)j * HV, Qc + (size_t)j * HV,
           RSb + (size_t)sp * HV, RSb + (size_t)s * HV,
           hinF + (size_t)s * HV, trio + (size_t)(30 + s) * SLOT, nullptr, nullptr, red);
      gbar(ctr, p++);
      int d2 = (j == 0) ? (index + 1) : (9 + vhv);
      if (j > 0) vhv++;
      phHH(Whh, trio + (size_t)(30 + s) * SLOT, hinF + (size_t)s * HV, gi_i, b_hh,
           trio + (size_t)d2 * SLOT,
           (j > 0) ? (Xe + (size_t)(sid0 + index - j) * NB * KE) : nullptr, red);
      gbar(ctr, p++);
      prevSlab = d2;
    }
    if (index < 7) {
      phGM(Wgm, trio + (size_t)(index + 1) * SLOT, 1, 0, 0, dep, gate_b, map_b,
           nullptr, nullptr, nullptr, nullptr, nullptr, nullptr,
           Pc + (size_t)index * HV, Qc + (size_t)index * HV, red);
      gbar(ctr, p++);
    }
  }
}

// ---------------- deferred MFMA kernels (unchanged) ----------------

__global__ __launch_bounds__(256) void kR(const u16* __restrict__ Wr3,
                                          const u16* __restrict__ Bsrc,
                                          _Float16* __restrict__ R) {
  __shared__ u16 sA[2][128 * 32];
  __shared__ u16 sB[2][128 * 32];
  const int t = threadIdx.x, w = t >> 6, l = t & 63, quad = l >> 4, lan = l & 15;
  const int mB = blockIdx.x * 128, nB0 = blockIdx.y * 128;
  const int qs = quad ^ ((lan >> 1) & 3);
  const int sseg = (l & 3) ^ ((l >> 3) & 3);
  const u16 *gA0, *gA1, *gB0, *gB1;
  {
    int r0 = (w * 2 + 0) * 16 + (l >> 2), r1 = (w * 2 + 1) * 16 + (l >> 2);
    gA0 = Wr3 + (size_t)(mB + r0) * KT + sseg * 8;
    gA1 = Wr3 + (size_t)(mB + r1) * KT + sseg * 8;
    gB0 = Bsrc + (size_t)(nB0 + r0) * KT + sseg * 8;
    gB1 = Bsrc + (size_t)(nB0 + r1) * KT + sseg * 8;
  }
  f32x4 acc[2][8];
#pragma unroll
  for (int mt = 0; mt < 2; ++mt)
#pragma unroll
    for (int ns = 0; ns < 8; ++ns) acc[mt][ns] = (f32x4){0.f,0.f,0.f,0.f};
  async_copy16(gA0, &sA[0][(w * 2 + 0) * 512]);
  async_copy16(gA1, &sA[0][(w * 2 + 1) * 512]);
  async_copy16(gB0, &sB[0][(w * 2 + 0) * 512]);
  async_copy16(gB1, &sB[0][(w * 2 + 1) * 512]);
  for (int c = 0; c < 48; ++c) {
    __syncthreads();
    if (c + 1 < 48) {
      int nb = (c + 1) & 1, off = (c + 1) * 32;
      async_copy16(gA0 + off, &sA[nb][(w * 2 + 0) * 512]);
      async_copy16(gA1 + off, &sA[nb][(w * 2 + 1) * 512]);
      async_copy16(gB0 + off, &sB[nb][(w * 2 + 0) * 512]);
      async_copy16(gB1 + off, &sB[nb][(w * 2 + 1) * 512]);
    }
    const u16* bufA = sA[c & 1];
    const u16* bufB = sB[c & 1];
    bf16x8v av[2];
#pragma unroll
    for (int mt = 0; mt < 2; ++mt)
      av[mt] = *(const bf16x8v*)&bufA[(w * 32 + mt * 16 + lan) * 32 + qs * 8];
#pragma unroll
    for (int ns = 0; ns < 8; ++ns) {
      bf16x8v bv = *(const bf16x8v*)&bufB[(ns * 16 + lan) * 32 + qs * 8];
#pragma unroll
      for (int mt = 0; mt < 2; ++mt) acc[mt][ns] = mfma_bf(av[mt], bv, acc[mt][ns]);
    }
  }
#pragma unroll
  for (int ns = 0; ns < 8; ++ns) {
    int col = nB0 + ns * 16 + lan;
#pragma unroll
    for (int mt = 0; mt < 2; ++mt) {
      int m0 = mB + w * 32 + mt * 16 + quad * 4;
      f16x4v rv;
#pragma unroll
      for (int reg = 0; reg < 4; ++reg) rv[reg] = (_Float16)acc[mt][ns][reg];
      *(f16x4v*)&R[(size_t)col * 2048 + m0] = rv;
    }
  }
}

__global__ __launch_bounds__(256) void kEdge(const _Float16* __restrict__ Wl,
                                             const _Float16* __restrict__ Xe,
                                             const _Float16* __restrict__ R,
                                             const float* __restrict__ ae_b1,
                                             const float* __restrict__ ae_w2,
                                             float* __restrict__ out0) {
  __shared__ u16 sA[2][128 * 32];
  __shared__ u16 sB[2][128 * 32];
  __shared__ float shW[4][8][16];
  const int t = threadIdx.x, w = t >> 6, l = t & 63, quad = l >> 4, lan = l & 15;
  const int mB = blockIdx.x * 128, nB0 = blockIdx.y * 128;
  const int qs = quad ^ ((lan >> 1) & 3);
  const int sseg = (l & 3) ^ ((l >> 3) & 3);
  int sid = blockIdx.y >> 1;
  int idec = 1, bse = 0;
  while (sid >= bse + idec) { bse += idec; idec++; }
  int jdec = idec - 1 - (sid - bse);
  const _Float16 *gA0, *gA1, *gB0, *gB1;
  {
    int r0 = (w * 2 + 0) * 16 + (l >> 2), r1 = (w * 2 + 1) * 16 + (l >> 2);
    gA0 = Wl + (size_t)(mB + r0) * KE + sseg * 8;
    gA1 = Wl + (size_t)(mB + r1) * KE + sseg * 8;
    gB0 = Xe + (size_t)(nB0 + r0) * KE + sseg * 8;
    gB1 = Xe + (size_t)(nB0 + r1) * KE + sseg * 8;
  }
  f32x4 acc[2][8];
#pragma unroll
  for (int mt = 0; mt < 2; ++mt)
#pragma unroll
    for (int ns = 0; ns < 8; ++ns) acc[mt][ns] = (f32x4){0.f,0.f,0.f,0.f};
  async_copy16(gA0, &sA[0][(w * 2 + 0) * 512]);
  async_copy16(gA1, &sA[0][(w * 2 + 1) * 512]);
  async_copy16(gB0, &sB[0][(w * 2 + 0) * 512]);
  async_copy16(gB1, &sB[0][(w * 2 + 1) * 512]);
  for (int c = 0; c < 16; ++c) {
    __syncthreads();
    if (c + 1 < 16) {
      int nb = (c + 1) & 1, off = (c + 1) * 32;
      async_copy16(gA0 + off, &sA[nb][(w * 2 + 0) * 512]);
      async_copy16(gA1 + off, &sA[nb][(w * 2 + 1) * 512]);
      async_copy16(gB0 + off, &sB[nb][(w * 2 + 0) * 512]);
      async_copy16(gB1 + off, &sB[nb][(w * 2 + 1) * 512]);
    }
    const u16* bufA = sA[c & 1];
    const u16* bufB = sB[c & 1];
    f16x8v av[2];
#pragma unroll
    for (int mt = 0; mt < 2; ++mt)
      av[mt] = *(const f16x8v*)&bufA[(w * 32 + mt * 16 + lan) * 32 + qs * 8];
#pragma unroll
    for (int ns = 0; ns < 8; ++ns) {
      f16x8v bv = *(const f16x8v*)&bufB[(ns * 16 + lan) * 32 + qs * 8];
#pragma unroll
      for (int mt = 0; mt < 2; ++mt) acc[mt][ns] = mfma_h(av[mt], bv, acc[mt][ns]);
    }
  }
  float b1v[2][4], w2v[2][4];
#pragma unroll
  for (int mt = 0; mt < 2; ++mt) {
    int m0 = mB + w * 32 + mt * 16 + quad * 4;
#pragma unroll
    for (int reg = 0; reg < 4; ++reg) {
      int m = m0 + reg;
      b1v[mt][reg] = (m < NH4) ? ae_b1[m] : 0.f;
      w2v[mt][reg] = (m < NH4) ? ae_w2[m] : 0.f;
    }
  }
#pragma unroll
  for (int ns = 0; ns < 8; ++ns) {
    int bcol = (nB0 + ns * 16 + lan) & 255;
    const _Float16* Rp = R + (size_t)(jdec * 256 + bcol) * 2048 + mB + w * 32;
    float s = 0.f;
#pragma unroll
    for (int mt = 0; mt < 2; ++mt) {
      f16x4v rv = *(const f16x4v*)&Rp[mt * 16 + quad * 4];
#pragma unroll
      for (int reg = 0; reg < 4; ++reg) {
        float v = acc[mt][ns][reg] + (float)rv[reg] + b1v[mt][reg];
        if (v > 0.f) s += v * w2v[mt][reg];
      }
    }
    s += __shfl_xor(s, 16);
    s += __shfl_xor(s, 32);
    if (quad == 0) shW[w][ns][lan] = s;
  }
  __syncthreads();
  if (t < 128) {
    int ns = t >> 4, ln = t & 15;
    float tot = shW[0][ns][ln] + shW[1][ns][ln] + shW[2][ns][ln] + shW[3][ns][ln];
    int b = (nB0 + ln + ns * 16) & 255;
    atomicAdd(&out0[b * 64 + idec * 8 + jdec], tot);
  }
}

__global__ __launch_bounds__(256) void kLogA(const u16* __restrict__ Wav1,
                                             const u16* __restrict__ Bsrc,
                                             const float* __restrict__ av_b1,
                                             _Float16* __restrict__ t1) {
  __shared__ u16 sA[2][128 * 32];
  __shared__ u16 sB[2][128 * 32];
  const int t = threadIdx.x, w = t >> 6, l = t & 63, quad = l >> 4, lan = l & 15;
  const int mB = blockIdx.x * 128, nB0 = blockIdx.y * 128;
  const int qs = quad ^ ((lan >> 1) & 3);
  const int sseg = (l & 3) ^ ((l >> 3) & 3);
  const u16 *gA0, *gA1, *gB0, *gB1;
  {
    int r0 = (w * 2 + 0) * 16 + (l >> 2), r1 = (w * 2 + 1) * 16 + (l >> 2);
    gA0 = Wav1 + (size_t)(mB + r0) * KT + sseg * 8;
    gA1 = Wav1 + (size_t)(mB + r1) * KT + sseg * 8;
    gB0 = Bsrc + (size_t)(nB0 + r0) * KT + sseg * 8;
    gB1 = Bsrc + (size_t)(nB0 + r1) * KT + sseg * 8;
  }
  f32x4 acc[2][8];
#pragma unroll
  for (int mt = 0; mt < 2; ++mt)
#pragma unroll
    for (int ns = 0; ns < 8; ++ns) acc[mt][ns] = (f32x4){0.f,0.f,0.f,0.f};
  async_copy16(gA0, &sA[0][(w * 2 + 0) * 512]);
  async_copy16(gA1, &sA[0][(w * 2 + 1) * 512]);
  async_copy16(gB0, &sB[0][(w * 2 + 0) * 512]);
  async_copy16(gB1, &sB[0][(w * 2 + 1) * 512]);
  for (int c = 0; c < 48; ++c) {
    __syncthreads();
    if (c + 1 < 48) {
      int nb = (c + 1) & 1, off = (c + 1) * 32;
      async_copy16(gA0 + off, &sA[nb][(w * 2 + 0) * 512]);
      async_copy16(gA1 + off, &sA[nb][(w * 2 + 1) * 512]);
      async_copy16(gB0 + off, &sB[nb][(w * 2 + 0) * 512]);
      async_copy16(gB1 + off, &sB[nb][(w * 2 + 1) * 512]);
    }
    const u16* bufA = sA[c & 1];
    const u16* bufB = sB[c & 1];
    bf16x8v av[2];
#pragma unroll
    for (int mt = 0; mt < 2; ++mt)
      av[mt] = *(const bf16x8v*)&bufA[(w * 32 + mt * 16 + lan) * 32 + qs * 8];
#pragma unroll
    for (int ns = 0; ns < 8; ++ns) {
      bf16x8v bv = *(const bf16x8v*)&bufB[(ns * 16 + lan) * 32 + qs * 8];
#pragma unroll
      for (int mt = 0; mt < 2; ++mt) acc[mt][ns] = mfma_bf(av[mt], bv, acc[mt][ns]);
    }
  }
#pragma unroll
  for (int ns = 0; ns < 8; ++ns) {
    int col = nB0 + ns * 16 + lan;
#pragma unroll
    for (int mt = 0; mt < 2; ++mt) {
      int m0 = mB + w * 32 + mt * 16 + quad * 4;
      f16x4v rv;
#pragma unroll
      for (int reg = 0; reg < 4; ++reg) {
        int m = m0 + reg;
        float v = acc[mt][ns][reg] + ((m < NH2) ? av_b1[m] : 0.f);
        rv[reg] = (_Float16)(v > 0.f ? v : 0.f);
      }
      *(f16x4v*)&t1[(size_t)col * 1024 + m0] = rv;
    }
  }
}

__global__ __launch_bounds__(256) void kSoft(const _Float16* __restrict__ t1,
                                             const float* __restrict__ av_w2,
                                             const float* __restrict__ av_b2,
                                             float* __restrict__ out1) {
  const int t = threadIdx.x, w = t >> 6, l = t & 63;
  int col = blockIdx.x * 4 + w;
  const _Float16* trow = t1 + (size_t)col * 1024;
  float s[8] = {};
  for (int i = 0; i < 16; ++i) {
    int k = i * 64 + l;
    if (k < NH2) {
      float v = (float)trow[k];
#pragma unroll
      for (int c = 0; c < 8; ++c) s[c] += v * av_w2[c * NH2 + k];
    }
  }
#pragma unroll
  for (int c = 0; c < 8; ++c) {
    s[c] += __shfl_xor(s[c], 32);
    s[c] += __shfl_xor(s[c], 16);
    s[c] += __shfl_xor(s[c], 8);
    s[c] += __shfl_xor(s[c], 4);
    s[c] += __shfl_xor(s[c], 2);
    s[c] += __shfl_xor(s[c], 1);
  }
  if (l == 0) {
    float lg[8], mx = -1e30f;
#pragma unroll
    for (int c = 0; c < 8; ++c) { lg[c] = s[c] + av_b2[c]; mx = fmaxf(mx, lg[c]); }
    float den = 0.f;
#pragma unroll
    for (int c = 0; c < 8; ++c) den += __expf(lg[c] - mx);
    int idx = col >> 8, b = col & 255;
#pragma unroll
    for (int c = 0; c < 8; ++c)
      out1[(b * NS + idx) * NC + c] = __expf(lg[c] - mx) / den;
  }
}

// ---------------- host ----------------

extern "C" void kernel_launch(void* const* d_in, const int* in_sizes, int n_in,
                              void* d_out, int out_size, void* d_ws, size_t ws_size,
                              hipStream_t stream) {
  (void)in_sizes; (void)n_in; (void)out_size; (void)ws_size;
  const float* z      = (const float*)d_in[0];
  const float* dep    = (const float*)d_in[1];
  const float* ne     = (const float*)d_in[2];
  const float* lin1_w = (const float*)d_in[3];
  const float* lin1_b = (const float*)d_in[4];
  const float* av_w1  = (const float*)d_in[5];
  const float* av_b1  = (const float*)d_in[6];
  const float* av_w2  = (const float*)d_in[7];
  const float* av_b2  = (const float*)d_in[8];
  const float* ae_w1  = (const float*)d_in[9];
  const float* ae_b1  = (const float*)d_in[10];
  const float* ae_w2  = (const float*)d_in[11];
  const float* ae_b2  = (const float*)d_in[12];
  const float* gate_w = (const float*)d_in[13];
  const float* gate_b = (const float*)d_in[14];
  const float* map_w  = (const float*)d_in[15];
  const float* map_b  = (const float*)d_in[16];
  const float* w_ih   = (const float*)d_in[17];
  const float* w_hh   = (const float*)d_in[18];
  const float* b_ih   = (const float*)d_in[19];
  const float* b_hh   = (const float*)d_in[20];

  float* out0 = (float*)d_out;
  float* out1 = out0 + NB * NS * NS;

  const size_t SLOT = (size_t)NB * KT;
  char* p = (char*)d_ws;
  u16* trio = (u16*)p;            p += 58 * SLOT * 2;                 // 58 trio slabs
  _Float16* Xe = (_Float16*)p;    p += (size_t)28 * NB * KE * 2;
  u16* Wgm  = (u16*)p;            p += (size_t)1024 * KT * 2;
  u16* Whh  = (u16*)p;            p += (size_t)1536 * KT * 2;
  u16* Wav1 = (u16*)p;            p += (size_t)1024 * KT * 2;
  u16* Wr3  = (u16*)p;            p += (size_t)2048 * KT * 2;
  _Float16* Wl = (_Float16*)p;    p += (size_t)2048 * KE * 2;
  _Float16* R  = (_Float16*)p;    p += (size_t)2048 * 2048 * 2;
  _Float16* t1 = (_Float16*)p;    p += (size_t)2048 * 1024 * 2;
  float* Pc   = (float*)p;        p += (size_t)8 * HV * 4;
  float* Qc   = (float*)p;        p += (size_t)8 * HV * 4;
  float* RSb  = (float*)p;        p += (size_t)28 * HV * 4;
  float* hinF = (float*)p;        p += (size_t)28 * HV * 4;
  float* g0   = (float*)p;        p += (size_t)HV * 4;
  float* giN  = (float*)p;        p += (size_t)8 * NH3 * NB * 4;
  float* giT  = (float*)p;        p += (size_t)8 * NB * KT * 4;
  int* ctr    = (int*)p;          p += 512;

  // init (5 launches)
  kPack<<<7680, 256, 0, stream>>>(gate_w, map_w, w_hh, av_w1, ae_w1, Wgm, Whh, Wav1, Wr3, Wl);
  kPadZ<<<86, 256, 0, stream>>>(trio, Xe);
  kInit0<<<65, 256, 0, stream>>>(out0, ae_b2, ctr);
  kLin1<<<256, 256, 0, stream>>>(z, lin1_w, lin1_b, g0, trio);
  kGiAll<<<NH3, 256, 0, stream>>>(ne, w_ih, b_ih, giN, giT);

  // the entire recurrence: one persistent kernel, release-only barriers,
  // single-assignment cross-phase buffers (no acquire/invalidate needed)
  kLoop<<<256, 256, 0, stream>>>(Wgm, Whh, dep, gate_b, map_b, b_hh,
                                 giN, giT, g0, trio, RSb, hinF, Pc, Qc, Xe, ctr);

  // deferred (4 launches)
  kR<<<dim3(16, 16), 256, 0, stream>>>(Wr3, trio + 1 * SLOT, R);
  kEdge<<<dim3(16, 56), 256, 0, stream>>>(Wl, Xe, R, ae_b1, ae_w2, out0);
  kLogA<<<dim3(8, 16), 256, 0, stream>>>(Wav1, trio, av_b1, t1);
  kSoft<<<512, 256, 0, stream>>>(t1, av_w2, av_b2, out1);
}

// Round 7
// 879.268 us; speedup vs baseline: 1.8951x; 1.8951x over previous
//
#include <hip/hip_runtime.h>
#include <math.h>

constexpr int NB  = 256;
constexpr int NS  = 8;
constexpr int NC  = 8;
constexpr int NH  = 501;
constexpr int NL  = 56;
constexpr int NH2 = 1002;
constexpr int NH3 = 1503;
constexpr int NH4 = 2004;
constexpr int KT  = 1536;   // trio K (3 x 512) bf16 hi/hi/lo . hi/lo/hi
constexpr int KE  = 512;    // fp16 snapshot K
constexpr int KA  = 1024;   // edge GEMM K ([hv ; nhs_j])
constexpr int HV  = 512 * 256;

typedef unsigned short u16;
typedef short bf16x8v __attribute__((ext_vector_type(8)));
typedef _Float16 f16x8v __attribute__((ext_vector_type(8)));
typedef _Float16 f16x4v __attribute__((ext_vector_type(4)));
typedef float f32x4 __attribute__((ext_vector_type(4)));

__device__ __forceinline__ float sigf(float x) { return 1.0f / (1.0f + __expf(-x)); }
__device__ __forceinline__ float tanh2(float x) { return 2.0f * sigf(2.0f * x) - 1.0f; }

__device__ __forceinline__ u16 f2bf(float x) {
  union { float f; unsigned u; } c; c.f = x;
  unsigned r = (c.u + 0x7fffu + ((c.u >> 16) & 1u)) >> 16;
  return (u16)r;
}
__device__ __forceinline__ float bf2f(u16 h) {
  union { float f; unsigned u; } c; c.u = ((unsigned)h) << 16; return c.f;
}

__device__ __forceinline__ void async_copy16(const void* g, void* l) {
  __builtin_amdgcn_global_load_lds(
      (const __attribute__((address_space(1))) unsigned int*)g,
      (__attribute__((address_space(3))) unsigned int*)l, 16, 0, 0);
}

__device__ __forceinline__ f32x4 mfma_bf(bf16x8v a, bf16x8v b, f32x4 c) {
  return __builtin_amdgcn_mfma_f32_16x16x32_bf16(a, b, c, 0, 0, 0);
}
__device__ __forceinline__ f32x4 mfma_h(f16x8v a, f16x8v b, f32x4 c) {
  return __builtin_amdgcn_mfma_f32_16x16x32_f16(a, b, c, 0, 0, 0);
}

__device__ __forceinline__ void storeTrio(u16* __restrict__ T, int b, int h0, const float v[4]) {
  size_t base = (size_t)b * KT;
  if (h0 + 3 < NH) {
    ushort4 hi4, lo4;
    u16 hi, lo;
    hi = f2bf(v[0]); lo = f2bf(v[0] - bf2f(hi)); hi4.x = hi; lo4.x = lo;
    hi = f2bf(v[1]); lo = f2bf(v[1] - bf2f(hi)); hi4.y = hi; lo4.y = lo;
    hi = f2bf(v[2]); lo = f2bf(v[2] - bf2f(hi)); hi4.z = hi; lo4.z = lo;
    hi = f2bf(v[3]); lo = f2bf(v[3] - bf2f(hi)); hi4.w = hi; lo4.w = lo;
    *(ushort4*)&T[base + h0]        = hi4;
    *(ushort4*)&T[base + 512 + h0]  = lo4;
    *(ushort4*)&T[base + 1024 + h0] = hi4;
  } else {
    for (int r = 0; r < 4; ++r) {
      int h = h0 + r;
      if (h < NH) {
        u16 hi = f2bf(v[r]); u16 lo = f2bf(v[r] - bf2f(hi));
        T[base + h] = hi; T[base + 512 + h] = lo; T[base + 1024 + h] = hi;
      }
    }
  }
}

// ---------------- pack ----------------
// rows: [0,1024) Wgm trio (gate 0..511, map 512..1023); [1024,2560) Whh trio (r,z,n);
// [2560,3584) Wav1 trio; [3584,5632) Wlr fp16 K=1024 ([left | right] of ae_w1)
__global__ __launch_bounds__(256) void kPack(
    const float* __restrict__ gate_w, const float* __restrict__ map_w,
    const float* __restrict__ w_hh, const float* __restrict__ av_w1,
    const float* __restrict__ ae_w1,
    u16* __restrict__ Wgm, u16* __restrict__ Whh, u16* __restrict__ Wav1,
    _Float16* __restrict__ Wlr) {
  int r = blockIdx.x;
  if (r < 3584) {
    for (int k = threadIdx.x; k < 512; k += 256) {
      float v = 0.f; u16* dst; int rr;
      if (r < 1024) {
        int h = (r < 512) ? r : r - 512;
        if (h < NH && k < NH) v = (r < 512) ? gate_w[h * NH + k] : map_w[h * NH + k];
        dst = Wgm; rr = r;
      } else if (r < 2560) {
        rr = r - 1024; int g = rr >> 9, h = rr & 511;
        if (h < NH && k < NH) v = w_hh[((size_t)g * NH + h) * NH + k];
        dst = Whh;
      } else {
        rr = r - 2560;
        if (rr < NH2 && k < NH) v = av_w1[(size_t)rr * NH + k];
        dst = Wav1;
      }
      u16 hi = f2bf(v); u16 lo = f2bf(v - bf2f(hi));
      dst[(size_t)rr * KT + k] = hi;
      dst[(size_t)rr * KT + 512 + k] = hi;
      dst[(size_t)rr * KT + 1024 + k] = lo;
    }
  } else {
    int m = r - 3584;
    for (int k = threadIdx.x; k < KA; k += 256) {
      float v = 0.f;
      if (m < NH4) {
        if (k < 512) { if (k < NH) v = ae_w1[(size_t)m * NH2 + k]; }
        else { int kk = k - 512; if (kk < NH) v = ae_w1[(size_t)m * NH2 + NH + kk]; }
      }
      Wlr[(size_t)m * KA + k] = (_Float16)v;
    }
  }
}

// ---------------- merged init ----------------
// blocks: [0,64) out0 ; [64,75) trio pad (11 slabs) ; [75,103) Xe pad (28) ;
// [103,110) Xn pad (7) ; [110,366) lin1 (col per block) ; [366,617) giAll (6 rows/blk)
__global__ __launch_bounds__(256) void kInit(
    float* __restrict__ out0, const float* __restrict__ ae_b2,
    u16* __restrict__ trio, _Float16* __restrict__ Xe, _Float16* __restrict__ Xn,
    const float* __restrict__ z, const float* __restrict__ lin1_w,
    const float* __restrict__ lin1_b, float* __restrict__ g0,
    const float* __restrict__ ne, const float* __restrict__ w_ih,
    const float* __restrict__ b_ih, float* __restrict__ giN, float* __restrict__ giT) {
  int blk = blockIdx.x, t = threadIdx.x;
  if (blk < 64) {
    int e = blk * 256 + t;
    int b = e >> 6, r = e & 63;
    int i = r >> 3, jj = r & 7;
    out0[b * 64 + i * 8 + jj] = (jj < i) ? ae_b2[0] : 0.f;
  } else if (blk < 75) {
    u16* T = trio + (size_t)(blk - 64) * ((size_t)NB * KT) + (size_t)t * KT;
#pragma unroll
    for (int seg = 0; seg < 3; ++seg)
      for (int h = NH; h < 512; ++h) T[seg * 512 + h] = 0;
  } else if (blk < 103) {
    _Float16* X = Xe + (size_t)(blk - 75) * NB * KE + (size_t)t * KE;
    for (int h = NH; h < 512; ++h) X[h] = (_Float16)0.f;
  } else if (blk < 110) {
    _Float16* X = Xn + (size_t)(blk - 103) * NB * KE + (size_t)t * KE;
    for (int h = NH; h < 512; ++h) X[h] = (_Float16)0.f;
  } else if (blk < 366) {
    int b = blk - 110;
    const float* zr = z + (size_t)b * NL;
    for (int h = t; h < NH; h += 256) {
      const float* wr = lin1_w + (size_t)h * NL;
      float acc = lin1_b[h];
#pragma unroll
      for (int l = 0; l < NL; ++l) acc += zr[l] * wr[l];
      g0[h * NB + b] = acc;
      u16 hi = f2bf(acc), lo = f2bf(acc - bf2f(hi));
      trio[(size_t)b * KT + h] = hi;
      trio[(size_t)b * KT + 512 + h] = lo;
      trio[(size_t)b * KT + 1024 + h] = hi;
    }
  } else {
    int r0 = (blk - 366) * 6, b = t;
    for (int rr = 0; rr < 6; ++rr) {
      int r = r0 + rr;
      if (r >= NH3) break;
      int g = (r >= NH2) ? 2 : ((r >= NH) ? 1 : 0);
      int h = r - g * NH;
      float wv[8];
#pragma unroll
      for (int c = 0; c < 8; ++c) wv[c] = w_ih[r * NC + c];
      float bb = b_ih[r];
      for (int idx = 0; idx < 8; ++idx) {
        float acc = bb;
#pragma unroll
        for (int c = 0; c < 8; ++c) acc += ne[b * 64 + idx * 8 + c] * wv[c];
        giN[((size_t)idx * NH3 + r) * NB + b] = acc;
        giT[((size_t)idx * NB + b) * KT + g * 512 + h] = acc;
      }
    }
  }
}

// ---------------- loop kernels (one launch per phase; 256 flat blocks) ----------------

// kGMT: transition i -> i+1. GEMM gate/map on final-hv trio; epilogue stores Pc/Qc,
// computes first-inner-step hin (fj from registers!) + fresh RS; idle waves: hv0 -> Xe.
__global__ __launch_bounds__(256) void kGMT(
    const u16* __restrict__ Wgm, const u16* __restrict__ Bsrc,
    float* __restrict__ PcO, float* __restrict__ QcO,
    const float* __restrict__ dep, const float* __restrict__ gate_b,
    const float* __restrict__ map_b, float* __restrict__ RS, u16* __restrict__ hinT,
    const float* __restrict__ giT, const float* __restrict__ b_hh,
    _Float16* __restrict__ Xe0, int index) {
  __shared__ f32x4 red[4 * 4 * 64];
  const int b = blockIdx.x, t = threadIdx.x, w = t >> 6, l = t & 63;
  const int quad = l >> 4, lan = l & 15;
  const int ht = b & 31, ct = b >> 5;
  const u16* Ag = Wgm + (size_t)(ht * 16 + lan) * KT;
  const u16* Am = Wgm + (size_t)(512 + ht * 16 + lan) * KT;
  const u16* B0 = Bsrc + (size_t)(ct * 32 + lan) * KT;
  const u16* B1 = Bsrc + (size_t)(ct * 32 + 16 + lan) * KT;
  const int kb = w * 384 + quad * 8;
  f32x4 a0 = {0.f,0.f,0.f,0.f}, a1 = a0, a2 = a0, a3 = a0;
#pragma unroll 4
  for (int ks = 0; ks < 12; ++ks) {
    int k = kb + ks * 32;
    bf16x8v bg = *(const bf16x8v*)&B0[k];
    bf16x8v bh = *(const bf16x8v*)&B1[k];
    bf16x8v ag = *(const bf16x8v*)&Ag[k];
    bf16x8v am = *(const bf16x8v*)&Am[k];
    a0 = mfma_bf(ag, bg, a0); a1 = mfma_bf(ag, bh, a1);
    a2 = mfma_bf(am, bg, a2); a3 = mfma_bf(am, bh, a3);
  }
  red[(w * 4 + 0) * 64 + l] = a0;
  red[(w * 4 + 1) * 64 + l] = a1;
  red[(w * 4 + 2) * 64 + l] = a2;
  red[(w * 4 + 3) * 64 + l] = a3;
  __syncthreads();
  if (w < 2) {
    int ns = w;
    f32x4 G = red[(0 * 4 + ns) * 64 + l] + red[(1 * 4 + ns) * 64 + l] +
              red[(2 * 4 + ns) * 64 + l] + red[(3 * 4 + ns) * 64 + l];
    f32x4 M = red[(0 * 4 + 2 + ns) * 64 + l] + red[(1 * 4 + 2 + ns) * 64 + l] +
              red[(2 * 4 + 2 + ns) * 64 + l] + red[(3 * 4 + 2 + ns) * 64 + l];
    int c = ct * 32 + ns * 16 + lan;
    int h0 = ht * 16 + quad * 4;
    int j = index - 1;
    float dj = dep[c * 64 + index * 8 + j];
    float vout[4];
#pragma unroll
    for (int reg = 0; reg < 4; ++reg) {
      int h = h0 + reg; float v = 0.f;
      if (h < NH) {
        PcO[h * NB + c] = G[reg];
        QcO[h * NB + c] = M[reg];
        float gb = gate_b[h], mb = map_b[h];
        float kbv = sigf(gb) * mb;
        float fj = sigf(dj * G[reg] + gb) * (dj * M[reg] + mb);
        RS[h * NB + c] = fj;
        v = fj + 7.0f * kbv;   // fi = kb, cnt = 6  ->  fj + kb + 6*kb
      }
      vout[reg] = v;
    }
    storeTrio(hinT, c, h0, vout);
  } else {
    // waves 2..3: hv0 = gru(x_index, 0) -> Xe slot (elementwise from giT)
    int t2 = t - 128;
    int c = ct * 32 + (t2 & 31);
    int hb = t2 >> 5;              // 0..3
    const float* g = giT + ((size_t)index * NB + c) * KT;
#pragma unroll
    for (int k = 0; k < 4; ++k) {
      int h = ht * 16 + hb * 4 + k;
      if (h < NH) {
        float rr = sigf(g[h] + b_hh[h]);
        float zz = sigf(g[512 + h] + b_hh[NH + h]);
        float nn = tanh2(g[1024 + h] + rr * b_hh[2 * NH + h]);
        Xe0[(size_t)c * KE + h] = (_Float16)((1.f - zz) * nn);
      }
    }
  }
}

// kGM0: mid-inner-step gate/map GEMM; epilogue: RS += fj(cached Pc/Qc), hin trio.
__global__ __launch_bounds__(256) void kGM0(
    const u16* __restrict__ Wgm, const u16* __restrict__ Bsrc,
    const float* __restrict__ dep, const float* __restrict__ gate_b,
    const float* __restrict__ map_b,
    const float* __restrict__ Pcj, const float* __restrict__ Qcj,
    float* __restrict__ RS, u16* __restrict__ hinT, int index, int j) {
  __shared__ f32x4 red[4 * 4 * 64];
  const int b = blockIdx.x, t = threadIdx.x, w = t >> 6, l = t & 63;
  const int quad = l >> 4, lan = l & 15;
  const int ht = b & 31, ct = b >> 5;
  const u16* Ag = Wgm + (size_t)(ht * 16 + lan) * KT;
  const u16* Am = Wgm + (size_t)(512 + ht * 16 + lan) * KT;
  const u16* B0 = Bsrc + (size_t)(ct * 32 + lan) * KT;
  const u16* B1 = Bsrc + (size_t)(ct * 32 + 16 + lan) * KT;
  const int kb = w * 384 + quad * 8;
  f32x4 a0 = {0.f,0.f,0.f,0.f}, a1 = a0, a2 = a0, a3 = a0;
#pragma unroll 4
  for (int ks = 0; ks < 12; ++ks) {
    int k = kb + ks * 32;
    bf16x8v bg = *(const bf16x8v*)&B0[k];
    bf16x8v bh = *(const bf16x8v*)&B1[k];
    bf16x8v ag = *(const bf16x8v*)&Ag[k];
    bf16x8v am = *(const bf16x8v*)&Am[k];
    a0 = mfma_bf(ag, bg, a0); a1 = mfma_bf(ag, bh, a1);
    a2 = mfma_bf(am, bg, a2); a3 = mfma_bf(am, bh, a3);
  }
  red[(w * 4 + 0) * 64 + l] = a0;
  red[(w * 4 + 1) * 64 + l] = a1;
  red[(w * 4 + 2) * 64 + l] = a2;
  red[(w * 4 + 3) * 64 + l] = a3;
  __syncthreads();
  if (w < 2) {
    int ns = w;
    f32x4 G = red[(0 * 4 + ns) * 64 + l] + red[(1 * 4 + ns) * 64 + l] +
              red[(2 * 4 + ns) * 64 + l] + red[(3 * 4 + ns) * 64 + l];
    f32x4 M = red[(0 * 4 + 2 + ns) * 64 + l] + red[(1 * 4 + 2 + ns) * 64 + l] +
              red[(2 * 4 + 2 + ns) * 64 + l] + red[(3 * 4 + 2 + ns) * 64 + l];
    int c = ct * 32 + ns * 16 + lan;
    int h0 = ht * 16 + quad * 4;
    float dj = dep[c * 64 + index * 8 + j];
    float di = dep[c * 64 + index * 8 + index];
    float cnt = (float)(7 - (index - j));
    float vout[4];
#pragma unroll
    for (int reg = 0; reg < 4; ++reg) {
      int h = h0 + reg; float v = 0.f;
      if (h < NH) {
        float gb = gate_b[h], mb = map_b[h];
        float kbv = sigf(gb) * mb;
        float fj = sigf(dj * Pcj[h * NB + c] + gb) * (dj * Qcj[h * NB + c] + mb);
        float rs = RS[h * NB + c] + fj;
        RS[h * NB + c] = rs;
        float fi = sigf(di * G[reg] + gb) * (di * M[reg] + mb);
        v = rs + fi + cnt * kbv;
      }
      vout[reg] = v;
    }
    storeTrio(hinT, c, h0, vout);
  }
}

// kHHw: gru_hh GEMM + GRU combine. hid from hidF (fp32) or reconstructed from B trio.
__global__ __launch_bounds__(256) void kHHw(
    const u16* __restrict__ Whh, const u16* __restrict__ Bsrc,
    const float* __restrict__ hidF, const float* __restrict__ gi,
    const float* __restrict__ b_hh,
    u16* __restrict__ dstT, _Float16* __restrict__ XeSlot, _Float16* __restrict__ XnSlot) {
  __shared__ f32x4 red[4 * 6 * 64];
  const int b = blockIdx.x, t = threadIdx.x, w = t >> 6, l = t & 63;
  const int quad = l >> 4, lan = l & 15;
  const int ht = b & 31, ct = b >> 5;
  const u16* Ar = Whh + (size_t)(ht * 16 + lan) * KT;
  const u16* Az = Whh + (size_t)(512 + ht * 16 + lan) * KT;
  const u16* An = Whh + (size_t)(1024 + ht * 16 + lan) * KT;
  const u16* B0 = Bsrc + (size_t)(ct * 32 + lan) * KT;
  const u16* B1 = Bsrc + (size_t)(ct * 32 + 16 + lan) * KT;
  const int kb = w * 384 + quad * 8;
  f32x4 r0 = {0.f,0.f,0.f,0.f}, r1 = r0, z0 = r0, z1 = r0, n0 = r0, n1 = r0;
#pragma unroll 4
  for (int ks = 0; ks < 12; ++ks) {
    int k = kb + ks * 32;
    bf16x8v bg = *(const bf16x8v*)&B0[k];
    bf16x8v bh = *(const bf16x8v*)&B1[k];
    bf16x8v ar = *(const bf16x8v*)&Ar[k];
    bf16x8v az = *(const bf16x8v*)&Az[k];
    bf16x8v an = *(const bf16x8v*)&An[k];
    r0 = mfma_bf(ar, bg, r0); r1 = mfma_bf(ar, bh, r1);
    z0 = mfma_bf(az, bg, z0); z1 = mfma_bf(az, bh, z1);
    n0 = mfma_bf(an, bg, n0); n1 = mfma_bf(an, bh, n1);
  }
  red[(w * 6 + 0) * 64 + l] = r0;
  red[(w * 6 + 1) * 64 + l] = r1;
  red[(w * 6 + 2) * 64 + l] = z0;
  red[(w * 6 + 3) * 64 + l] = z1;
  red[(w * 6 + 4) * 64 + l] = n0;
  red[(w * 6 + 5) * 64 + l] = n1;
  __syncthreads();
  if (w < 2) {
    int ns = w;
    f32x4 Rr = red[(0 * 6 + 0 + ns) * 64 + l] + red[(1 * 6 + 0 + ns) * 64 + l] +
               red[(2 * 6 + 0 + ns) * 64 + l] + red[(3 * 6 + 0 + ns) * 64 + l];
    f32x4 Rz = red[(0 * 6 + 2 + ns) * 64 + l] + red[(1 * 6 + 2 + ns) * 64 + l] +
               red[(2 * 6 + 2 + ns) * 64 + l] + red[(3 * 6 + 2 + ns) * 64 + l];
    f32x4 Rn = red[(0 * 6 + 4 + ns) * 64 + l] + red[(1 * 6 + 4 + ns) * 64 + l] +
               red[(2 * 6 + 4 + ns) * 64 + l] + red[(3 * 6 + 4 + ns) * 64 + l];
    int c = ct * 32 + ns * 16 + lan;
    int h0 = ht * 16 + quad * 4;
    float vout[4];
#pragma unroll
    for (int reg = 0; reg < 4; ++reg) {
      int h = h0 + reg; float v = 0.f;
      if (h < NH) {
        float ir = gi[h * NB + c];
        float iz = gi[(NH + h) * NB + c];
        float inn = gi[(2 * NH + h) * NB + c];
        float rr = sigf(ir + Rr[reg] + b_hh[h]);
        float zz = sigf(iz + Rz[reg] + b_hh[NH + h]);
        float nn = tanh2(inn + rr * (Rn[reg] + b_hh[2 * NH + h]));
        float hd;
        if (hidF) hd = hidF[h * NB + c];
        else hd = bf2f(Bsrc[(size_t)c * KT + h]) + bf2f(Bsrc[(size_t)c * KT + 512 + h]);
        v = (1.f - zz) * nn + zz * hd;
      }
      vout[reg] = v;
    }
    storeTrio(dstT, c, h0, vout);
    if (XeSlot || XnSlot) {
      if (h0 + 3 < NH) {
        f16x4v xv; xv[0] = (_Float16)vout[0]; xv[1] = (_Float16)vout[1];
        xv[2] = (_Float16)vout[2]; xv[3] = (_Float16)vout[3];
        if (XeSlot) *(f16x4v*)&XeSlot[(size_t)c * KE + h0] = xv;
        if (XnSlot) *(f16x4v*)&XnSlot[(size_t)c * KE + h0] = xv;
      } else {
        for (int reg = 0; reg < 4; ++reg)
          if (h0 + reg < NH) {
            if (XeSlot) XeSlot[(size_t)c * KE + h0 + reg] = (_Float16)vout[reg];
            if (XnSlot) XnSlot[(size_t)c * KE + h0 + reg] = (_Float16)vout[reg];
          }
      }
    }
  }
}

// ---------------- deferred ----------------

// kEdge: [Wl|Wr] @ [Xe_s ; Xn_j]  (K=1024 fp16) -> relu(+b1) . ae_w2 -> atomicAdd out0
__global__ __launch_bounds__(256) void kEdge(const _Float16* __restrict__ Wlr,
                                             const _Float16* __restrict__ Xe,
                                             const _Float16* __restrict__ Xn,
                                             const float* __restrict__ ae_b1,
                                             const float* __restrict__ ae_w2,
                                             float* __restrict__ out0) {
  __shared__ u16 sA[2][128 * 32];
  __shared__ u16 sB[2][128 * 32];
  __shared__ float shW[4][8][16];
  const int t = threadIdx.x, w = t >> 6, l = t & 63, quad = l >> 4, lan = l & 15;
  const int mB = blockIdx.x * 128, nB0 = blockIdx.y * 128;
  const int qs = quad ^ ((lan >> 1) & 3);
  const int sseg = (l & 3) ^ ((l >> 3) & 3);
  int sid = blockIdx.y >> 1;
  int idec = 1, bse = 0;
  while (sid >= bse + idec) { bse += idec; idec++; }
  int jdec = idec - 1 - (sid - bse);
  int r0 = (w * 2 + 0) * 16 + (l >> 2), r1 = (w * 2 + 1) * 16 + (l >> 2);
  const _Float16* gA0 = Wlr + (size_t)(mB + r0) * KA + sseg * 8;
  const _Float16* gA1 = Wlr + (size_t)(mB + r1) * KA + sseg * 8;
  const _Float16* Xe0 = Xe + (size_t)(nB0 + r0) * KE + sseg * 8;
  const _Float16* Xe1 = Xe + (size_t)(nB0 + r1) * KE + sseg * 8;
  const _Float16* Xn0 = Xn + ((size_t)jdec * NB + ((nB0 + r0) & 255)) * KE + sseg * 8;
  const _Float16* Xn1 = Xn + ((size_t)jdec * NB + ((nB0 + r1) & 255)) * KE + sseg * 8;
  f32x4 acc[2][8];
#pragma unroll
  for (int mt = 0; mt < 2; ++mt)
#pragma unroll
    for (int ns = 0; ns < 8; ++ns) acc[mt][ns] = (f32x4){0.f,0.f,0.f,0.f};
  async_copy16(gA0, &sA[0][(w * 2 + 0) * 512]);
  async_copy16(gA1, &sA[0][(w * 2 + 1) * 512]);
  async_copy16(Xe0, &sB[0][(w * 2 + 0) * 512]);
  async_copy16(Xe1, &sB[0][(w * 2 + 1) * 512]);
  for (int c = 0; c < 32; ++c) {
    __syncthreads();
    if (c + 1 < 32) {
      int nb = (c + 1) & 1, cc = c + 1;
      async_copy16(gA0 + cc * 32, &sA[nb][(w * 2 + 0) * 512]);
      async_copy16(gA1 + cc * 32, &sA[nb][(w * 2 + 1) * 512]);
      const _Float16* b0 = (cc < 16) ? (Xe0 + cc * 32) : (Xn0 + (cc - 16) * 32);
      const _Float16* b1 = (cc < 16) ? (Xe1 + cc * 32) : (Xn1 + (cc - 16) * 32);
      async_copy16(b0, &sB[nb][(w * 2 + 0) * 512]);
      async_copy16(b1, &sB[nb][(w * 2 + 1) * 512]);
    }
    const u16* bufA = sA[c & 1];
    const u16* bufB = sB[c & 1];
    f16x8v av[2];
#pragma unroll
    for (int mt = 0; mt < 2; ++mt)
      av[mt] = *(const f16x8v*)&bufA[(w * 32 + mt * 16 + lan) * 32 + qs * 8];
#pragma unroll
    for (int ns = 0; ns < 8; ++ns) {
      f16x8v bv = *(const f16x8v*)&bufB[(ns * 16 + lan) * 32 + qs * 8];
#pragma unroll
      for (int mt = 0; mt < 2; ++mt) acc[mt][ns] = mfma_h(av[mt], bv, acc[mt][ns]);
    }
  }
  float b1v[2][4], w2v[2][4];
#pragma unroll
  for (int mt = 0; mt < 2; ++mt) {
    int m0 = mB + w * 32 + mt * 16 + quad * 4;
#pragma unroll
    for (int reg = 0; reg < 4; ++reg) {
      int m = m0 + reg;
      b1v[mt][reg] = (m < NH4) ? ae_b1[m] : 0.f;
      w2v[mt][reg] = (m < NH4) ? ae_w2[m] : 0.f;
    }
  }
#pragma unroll
  for (int ns = 0; ns < 8; ++ns) {
    float s = 0.f;
#pragma unroll
    for (int mt = 0; mt < 2; ++mt) {
#pragma unroll
      for (int reg = 0; reg < 4; ++reg) {
        float v = acc[mt][ns][reg] + b1v[mt][reg];
        if (v > 0.f) s += v * w2v[mt][reg];
      }
    }
    s += __shfl_xor(s, 16);
    s += __shfl_xor(s, 32);
    if (quad == 0) shW[w][ns][lan] = s;
  }
  __syncthreads();
  if (t < 128) {
    int ns = t >> 4, ln = t & 15;
    float tot = shW[0][ns][ln] + shW[1][ns][ln] + shW[2][ns][ln] + shW[3][ns][ln];
    int b = (nB0 + ln + ns * 16) & 255;
    atomicAdd(&out0[b * 64 + idec * 8 + jdec], tot);
  }
}

// kLogA: t1 = relu(av_w1 @ GS + b1); 64x128 tiles -> grid(16,16) = 256 blocks
__global__ __launch_bounds__(256) void kLogA(const u16* __restrict__ Wav1,
                                             const u16* __restrict__ Bsrc,
                                             const float* __restrict__ av_b1,
                                             _Float16* __restrict__ t1) {
  __shared__ u16 sA[2][64 * 32];
  __shared__ u16 sB[2][128 * 32];
  const int t = threadIdx.x, w = t >> 6, l = t & 63, quad = l >> 4, lan = l & 15;
  const int mB = blockIdx.x * 64, nB0 = blockIdx.y * 128;
  const int qs = quad ^ ((lan >> 1) & 3);
  const int sseg = (l & 3) ^ ((l >> 3) & 3);
  int rA = w * 16 + (l >> 2);
  int r0 = (w * 2 + 0) * 16 + (l >> 2), r1 = (w * 2 + 1) * 16 + (l >> 2);
  const u16* gA = Wav1 + (size_t)(mB + rA) * KT + sseg * 8;
  const u16* gB0 = Bsrc + (size_t)(nB0 + r0) * KT + sseg * 8;
  const u16* gB1 = Bsrc + (size_t)(nB0 + r1) * KT + sseg * 8;
  f32x4 acc[8];
#pragma unroll
  for (int ns = 0; ns < 8; ++ns) acc[ns] = (f32x4){0.f,0.f,0.f,0.f};
  async_copy16(gA, &sA[0][w * 512]);
  async_copy16(gB0, &sB[0][(w * 2 + 0) * 512]);
  async_copy16(gB1, &sB[0][(w * 2 + 1) * 512]);
  for (int c = 0; c < 48; ++c) {
    __syncthreads();
    if (c + 1 < 48) {
      int nb = (c + 1) & 1, off = (c + 1) * 32;
      async_copy16(gA + off, &sA[nb][w * 512]);
      async_copy16(gB0 + off, &sB[nb][(w * 2 + 0) * 512]);
      async_copy16(gB1 + off, &sB[nb][(w * 2 + 1) * 512]);
    }
    const u16* bufA = sA[c & 1];
    const u16* bufB = sB[c & 1];
    bf16x8v av = *(const bf16x8v*)&bufA[(w * 16 + lan) * 32 + qs * 8];
#pragma unroll
    for (int ns = 0; ns < 8; ++ns) {
      bf16x8v bv = *(const bf16x8v*)&bufB[(ns * 16 + lan) * 32 + qs * 8];
      acc[ns] = mfma_bf(av, bv, acc[ns]);
    }
  }
#pragma unroll
  for (int ns = 0; ns < 8; ++ns) {
    int col = nB0 + ns * 16 + lan;
    int m0 = mB + w * 16 + quad * 4;
    f16x4v rv;
#pragma unroll
    for (int reg = 0; reg < 4; ++reg) {
      int m = m0 + reg;
      float v = acc[ns][reg] + ((m < NH2) ? av_b1[m] : 0.f);
      rv[reg] = (_Float16)(v > 0.f ? v : 0.f);
    }
    *(f16x4v*)&t1[(size_t)col * 1024 + m0] = rv;
  }
}

__global__ __launch_bounds__(256) void kSoft(const _Float16* __restrict__ t1,
                                             const float* __restrict__ av_w2,
                                             const float* __restrict__ av_b2,
                                             float* __restrict__ out1) {
  const int t = threadIdx.x, w = t >> 6, l = t & 63;
  int col = blockIdx.x * 4 + w;
  const _Float16* trow = t1 + (size_t)col * 1024;
  float s[8] = {};
  for (int i = 0; i < 16; ++i) {
    int k = i * 64 + l;
    if (k < NH2) {
      float v = (float)trow[k];
#pragma unroll
      for (int c = 0; c < 8; ++c) s[c] += v * av_w2[c * NH2 + k];
    }
  }
#pragma unroll
  for (int c = 0; c < 8; ++c) {
    s[c] += __shfl_xor(s[c], 32);
    s[c] += __shfl_xor(s[c], 16);
    s[c] += __shfl_xor(s[c], 8);
    s[c] += __shfl_xor(s[c], 4);
    s[c] += __shfl_xor(s[c], 2);
    s[c] += __shfl_xor(s[c], 1);
  }
  if (l == 0) {
    float lg[8], mx = -1e30f;
#pragma unroll
    for (int c = 0; c < 8; ++c) { lg[c] = s[c] + av_b2[c]; mx = fmaxf(mx, lg[c]); }
    float den = 0.f;
#pragma unroll
    for (int c = 0; c < 8; ++c) den += __expf(lg[c] - mx);
    int idx = col >> 8, b = col & 255;
#pragma unroll
    for (int c = 0; c < 8; ++c)
      out1[(b * NS + idx) * NC + c] = __expf(lg[c] - mx) / den;
  }
}

// ---------------- host ----------------

extern "C" void kernel_launch(void* const* d_in, const int* in_sizes, int n_in,
                              void* d_out, int out_size, void* d_ws, size_t ws_size,
                              hipStream_t stream) {
  (void)in_sizes; (void)n_in; (void)out_size; (void)ws_size;
  const float* z      = (const float*)d_in[0];
  const float* dep    = (const float*)d_in[1];
  const float* ne     = (const float*)d_in[2];
  const float* lin1_w = (const float*)d_in[3];
  const float* lin1_b = (const float*)d_in[4];
  const float* av_w1  = (const float*)d_in[5];
  const float* av_b1  = (const float*)d_in[6];
  const float* av_w2  = (const float*)d_in[7];
  const float* av_b2  = (const float*)d_in[8];
  const float* ae_w1  = (const float*)d_in[9];
  const float* ae_b1  = (const float*)d_in[10];
  const float* ae_w2  = (const float*)d_in[11];
  const float* ae_b2  = (const float*)d_in[12];
  const float* gate_w = (const float*)d_in[13];
  const float* gate_b = (const float*)d_in[14];
  const float* map_w  = (const float*)d_in[15];
  const float* map_b  = (const float*)d_in[16];
  const float* w_ih   = (const float*)d_in[17];
  const float* w_hh   = (const float*)d_in[18];
  const float* b_ih   = (const float*)d_in[19];
  const float* b_hh   = (const float*)d_in[20];

  float* out0 = (float*)d_out;
  float* out1 = out0 + NB * NS * NS;

  const size_t SLOT = (size_t)NB * KT;   // u16 elems per trio slab
  char* p = (char*)d_ws;
  // trio slabs: 0..7 = GS (graph_state at index i); 8 = hinT; 9,10 = hv scratch
  u16* trio = (u16*)p;            p += 11 * SLOT * 2;
  _Float16* Xe = (_Float16*)p;    p += (size_t)28 * NB * KE * 2;
  _Float16* Xn = (_Float16*)p;    p += (size_t)7 * NB * KE * 2;
  u16* Wgm  = (u16*)p;            p += (size_t)1024 * KT * 2;
  u16* Whh  = (u16*)p;            p += (size_t)1536 * KT * 2;
  u16* Wav1 = (u16*)p;            p += (size_t)1024 * KT * 2;
  _Float16* Wlr = (_Float16*)p;   p += (size_t)2048 * KA * 2;
  _Float16* t1 = (_Float16*)p;    p += (size_t)2048 * 1024 * 2;
  float* Pc   = (float*)p;        p += (size_t)8 * HV * 4;
  float* Qc   = (float*)p;        p += (size_t)8 * HV * 4;
  float* RS   = (float*)p;        p += (size_t)HV * 4;
  float* g0   = (float*)p;        p += (size_t)HV * 4;
  float* giN  = (float*)p;        p += (size_t)8 * NH3 * NB * 4;
  float* giT  = (float*)p;        p += (size_t)8 * NB * KT * 4;

  u16* hinT = trio + 8 * SLOT;

  // init (2 launches)
  kPack<<<5632, 256, 0, stream>>>(gate_w, map_w, w_hh, av_w1, ae_w1, Wgm, Whh, Wav1, Wlr);
  kInit<<<617, 256, 0, stream>>>(out0, ae_b2, trio, Xe, Xn,
                                 z, lin1_w, lin1_b, g0, ne, w_ih, b_ih, giN, giT);

  // index 0: hv = gru(x0, graph_state0); final -> GS1 + Xn0
  kHHw<<<256, 256, 0, stream>>>(Whh, trio, g0, giN, b_hh,
                                trio + 1 * SLOT, nullptr, Xn);

  for (int i = 0; i <= 6; ++i) {
    int index = i + 1;
    int sid0 = index * (index - 1) / 2;
    const float* gi_i = giN + (size_t)index * NH3 * NB;
    // transition: Pc/Qc[i] from GS[i+1]; first-inner-step hin + RS; hv0 -> Xe
    kGMT<<<256, 256, 0, stream>>>(Wgm, trio + (size_t)(i + 1) * SLOT,
                                  Pc + (size_t)i * HV, Qc + (size_t)i * HV,
                                  dep, gate_b, map_b, RS, hinT, giT, b_hh,
                                  Xe + (size_t)sid0 * NB * KE, index);
    // first HH of this outer step (inner j = index-1)
    bool final1 = (index == 1);
    u16* dst = final1 ? (trio + 2 * SLOT) : (trio + 9 * SLOT);
    kHHw<<<256, 256, 0, stream>>>(Whh, hinT, nullptr, gi_i, b_hh, dst,
        (index - 1 > 0) ? (Xe + (size_t)(sid0 + 1) * NB * KE) : nullptr,
        final1 ? (Xn + (size_t)1 * NB * KE) : nullptr);
    u16* prev = dst;
    int par = 1;
    for (int j = index - 2; j >= 0; --j) {
      kGM0<<<256, 256, 0, stream>>>(Wgm, prev, dep, gate_b, map_b,
                                    Pc + (size_t)j * HV, Qc + (size_t)j * HV,
                                    RS, hinT, index, j);
      bool fin = (j == 0);
      u16* d2 = (fin && index <= 6) ? (trio + (size_t)(index + 1) * SLOT)
                                    : (trio + (size_t)(9 + par) * SLOT);
      kHHw<<<256, 256, 0, stream>>>(Whh, hinT, nullptr, gi_i, b_hh, d2,
          (j > 0) ? (Xe + (size_t)(sid0 + index - j) * NB * KE) : nullptr,
          (fin && index <= 6) ? (Xn + (size_t)index * NB * KE) : nullptr);
      prev = d2; par ^= 1;
    }
  }

  // deferred (3 launches)
  kLogA<<<dim3(16, 16), 256, 0, stream>>>(Wav1, trio, av_b1, t1);
  kSoft<<<512, 256, 0, stream>>>(t1, av_w2, av_b2, out1);
  kEdge<<<dim3(16, 56), 256, 0, stream>>>(Wlr, Xe, Xn, ae_b1, ae_w2, out0);
}